// Round 1
// baseline (1355.194 us; speedup 1.0000x reference)
//
#include <hip/hip_runtime.h>
#include <cstdint>
#include <cstddef>

#define N_TOK 8192
#define DDIM  1024
#define FDIM  4096
#define NEXP  8
#define CAP   1280
#define NGROUP 16
#define NSLOT (NGROUP * CAP)   // 20480

typedef __attribute__((ext_vector_type(8))) __bf16 bf16x8;
typedef __attribute__((ext_vector_type(4))) float  f32x4;

__device__ __forceinline__ unsigned short f2bf(float f) {
    unsigned int u = __float_as_uint(f);
    u += 0x7fffu + ((u >> 16) & 1u);   // RNE (inputs are finite, no NaN)
    return (unsigned short)(u >> 16);
}

__device__ __forceinline__ void async_cp16(const void* g, void* l) {
    __builtin_amdgcn_global_load_lds(
        (const __attribute__((address_space(1))) unsigned int*)g,
        (__attribute__((address_space(3))) unsigned int*)l, 16, 0, 0);
}

// ---------------- router: logits, softmax, top2, stats ----------------
__global__ __launch_bounds__(256) void router_kernel(
    const float* __restrict__ x, const float* __restrict__ gate_w,
    int* __restrict__ topk_idx, float* __restrict__ topk_w,
    float* __restrict__ stats)
{
    __shared__ float red[256][9];
    const int n = blockIdx.x;
    const int t = threadIdx.x;
    const float4 xv = *(const float4*)(x + (size_t)n * DDIM + t * 4);
#pragma unroll
    for (int e = 0; e < NEXP; e++) {
        const float4 gv = *(const float4*)(gate_w + (size_t)e * DDIM + t * 4);
        red[t][e] = xv.x * gv.x + xv.y * gv.y + xv.z * gv.z + xv.w * gv.w;
    }
    __syncthreads();
    for (int s = 128; s > 0; s >>= 1) {
        if (t < s) {
#pragma unroll
            for (int e = 0; e < NEXP; e++) red[t][e] += red[t + s][e];
        }
        __syncthreads();
    }
    if (t == 0) {
        float l[NEXP], p[NEXP];
        float m = -1e30f;
#pragma unroll
        for (int e = 0; e < NEXP; e++) { l[e] = red[0][e]; m = fmaxf(m, l[e]); }
        float sum = 0.f;
#pragma unroll
        for (int e = 0; e < NEXP; e++) { p[e] = expf(l[e] - m); sum += p[e]; }
        const float inv = 1.f / sum;
#pragma unroll
        for (int e = 0; e < NEXP; e++) p[e] *= inv;
        const float lse = m + logf(sum);
        int e1 = 0; float p1 = p[0];
#pragma unroll
        for (int e = 1; e < NEXP; e++) if (p[e] > p1) { p1 = p[e]; e1 = e; }
        int e2 = -1; float p2 = -1.f;
#pragma unroll
        for (int e = 0; e < NEXP; e++) if (e != e1 && p[e] > p2) { p2 = p[e]; e2 = e; }
        const float wsum = p1 + p2;
        topk_idx[n * 2 + 0] = e1; topk_idx[n * 2 + 1] = e2;
        topk_w[n * 2 + 0] = p1 / wsum; topk_w[n * 2 + 1] = p2 / wsum;
        float* sp = stats + (n & 63) * 17;
#pragma unroll
        for (int e = 0; e < NEXP; e++) atomicAdd(sp + e, p[e]);
        atomicAdd(sp + 8 + e1, 1.f);
        atomicAdd(sp + 8 + e2, 1.f);
        atomicAdd(sp + 16, lse * lse);
    }
}

// ---------------- positions: first-come cumsum per (k,e), capacity drop ----------------
__global__ __launch_bounds__(512) void pos_kernel(
    const int* __restrict__ topk_idx, const float* __restrict__ topk_w,
    int* __restrict__ slot_tok, float* __restrict__ w_slot)
{
    __shared__ int cnt[2][NEXP][256];
    const int t = threadIdx.x;
    for (int i = t; i < NSLOT; i += 512) { slot_tok[i] = -1; w_slot[i] = 0.f; }
    const int kk = t >> 8;
    const int c  = t & 255;
    int lc[NEXP];
#pragma unroll
    for (int e = 0; e < NEXP; e++) lc[e] = 0;
    const int base_n = c * 32;
    for (int i = 0; i < 32; i++) lc[topk_idx[(base_n + i) * 2 + kk]]++;
#pragma unroll
    for (int e = 0; e < NEXP; e++) cnt[kk][e][c] = lc[e];
    __syncthreads();
    if (t < 16) {                      // 16 serial exclusive scans of 256 chunks
        const int k2 = t >> 3, e = t & 7;
        int run = 0;
        for (int c2 = 0; c2 < 256; c2++) { int v = cnt[k2][e][c2]; cnt[k2][e][c2] = run; run += v; }
    }
    __syncthreads();
    int run[NEXP];
#pragma unroll
    for (int e = 0; e < NEXP; e++) run[e] = cnt[kk][e][c];
    for (int i = 0; i < 32; i++) {
        const int n = base_n + i;
        const int e = topk_idx[n * 2 + kk];
        const int p = run[e]++;
        if (p < CAP) {
            const int slot = (kk * NEXP + e) * CAP + p;
            slot_tok[slot] = n;
            w_slot[slot] = topk_w[n * 2 + kk];
        }
    }
}

// ---------------- dispatch: gather x rows -> bf16 disp ----------------
__global__ __launch_bounds__(128) void dispatch_kernel(
    const float* __restrict__ x, const int* __restrict__ slot_tok,
    unsigned short* __restrict__ disp)
{
    const int slot = blockIdx.x;
    const int t = threadIdx.x;
    const int token = slot_tok[slot];
    uint4 o = make_uint4(0u, 0u, 0u, 0u);
    if (token >= 0) {
        const float4* src = (const float4*)(x + (size_t)token * DDIM + t * 8);
        const float4 a = src[0];
        const float4 b = src[1];
        o.x = (unsigned)f2bf(a.x) | ((unsigned)f2bf(a.y) << 16);
        o.y = (unsigned)f2bf(a.z) | ((unsigned)f2bf(a.w) << 16);
        o.z = (unsigned)f2bf(b.x) | ((unsigned)f2bf(b.y) << 16);
        o.w = (unsigned)f2bf(b.z) | ((unsigned)f2bf(b.w) << 16);
    }
    *(uint4*)(disp + (size_t)slot * DDIM + t * 8) = o;
}

// ---------------- gemm1: act = bf16( silu(disp@Wg^T) * (disp@Wu^T) ) ----------------
// block tile 128x128, BK=32, 4 waves in 2x2, wave tile 64x64 per C
__global__ __launch_bounds__(256, 2) void gemm1_kernel(
    const unsigned short* __restrict__ disp,
    const float* __restrict__ wi_gate, const float* __restrict__ wi_up,
    unsigned short* __restrict__ act)
{
    __shared__ __align__(16) unsigned short smem[12288]; // A:0..4095  BG:4096..8191  BU:8192..12287
    const int b = blockIdx.x;
    const int g = b / 320;            // (k,e) group
    const int rem = b % 320;
    const int mb = rem / 32, nb = rem % 32;
    const int e = g & 7;
    const int t = threadIdx.x;
    const int wave = t >> 6, lane = t & 63;

    const unsigned short* Asrc = disp + (size_t)(g * CAP + mb * 128) * DDIM;
    const float* Bgsrc = wi_gate + (size_t)e * FDIM * DDIM + (size_t)(nb * 128) * DDIM;
    const float* Busrc = wi_up   + (size_t)e * FDIM * DDIM + (size_t)(nb * 128) * DDIM;

    const int arow = t >> 2;          // 0..63
    const int acol = (t & 3) * 8;     // bf16 elems
    const int brow = t >> 3;          // 0..31
    const int bcol = (t & 7) * 4;     // fp32 elems

    const f32x4 fzero = {0.f, 0.f, 0.f, 0.f};
    f32x4 accg[4][4], accu[4][4];
#pragma unroll
    for (int i = 0; i < 4; i++)
#pragma unroll
        for (int j = 0; j < 4; j++) { accg[i][j] = fzero; accu[i][j] = fzero; }

    const int wm = wave >> 1, wn = wave & 1;
    const int lrow = lane & 15, lk = lane >> 4;

    for (int k0 = 0; k0 < DDIM; k0 += 32) {
        __syncthreads();
        // A (bf16) via async global->LDS, 16B/lane, 2 issues cover 128x32
        async_cp16(Asrc + (size_t)arow * DDIM + k0 + acol,        &smem[wave * 512]);
        async_cp16(Asrc + (size_t)(arow + 64) * DDIM + k0 + acol, &smem[2048 + wave * 512]);
        // B gate/up (fp32) -> convert -> LDS bf16
#pragma unroll
        for (int p = 0; p < 4; p++) {
            const int r = p * 32 + brow;
            const float4 gv = *(const float4*)(Bgsrc + (size_t)r * DDIM + k0 + bcol);
            const float4 uv = *(const float4*)(Busrc + (size_t)r * DDIM + k0 + bcol);
            uint2 gp, up;
            gp.x = (unsigned)f2bf(gv.x) | ((unsigned)f2bf(gv.y) << 16);
            gp.y = (unsigned)f2bf(gv.z) | ((unsigned)f2bf(gv.w) << 16);
            up.x = (unsigned)f2bf(uv.x) | ((unsigned)f2bf(uv.y) << 16);
            up.y = (unsigned)f2bf(uv.z) | ((unsigned)f2bf(uv.w) << 16);
            *(uint2*)&smem[4096 + r * 32 + bcol] = gp;
            *(uint2*)&smem[8192 + r * 32 + bcol] = up;
        }
        __syncthreads();
        bf16x8 af[4], bgf[4], buf2[4];
#pragma unroll
        for (int i = 0; i < 4; i++)
            af[i] = *(const bf16x8*)&smem[(wm * 64 + i * 16 + lrow) * 32 + lk * 8];
#pragma unroll
        for (int j = 0; j < 4; j++) {
            bgf[j]  = *(const bf16x8*)&smem[4096 + (wn * 64 + j * 16 + lrow) * 32 + lk * 8];
            buf2[j] = *(const bf16x8*)&smem[8192 + (wn * 64 + j * 16 + lrow) * 32 + lk * 8];
        }
#pragma unroll
        for (int i = 0; i < 4; i++)
#pragma unroll
            for (int j = 0; j < 4; j++) {
                accg[i][j] = __builtin_amdgcn_mfma_f32_16x16x32_bf16(af[i], bgf[j],  accg[i][j], 0, 0, 0);
                accu[i][j] = __builtin_amdgcn_mfma_f32_16x16x32_bf16(af[i], buf2[j], accu[i][j], 0, 0, 0);
            }
    }
    // epilogue: silu(g)*u -> bf16 act
#pragma unroll
    for (int i = 0; i < 4; i++)
#pragma unroll
        for (int r = 0; r < 4; r++) {
            const int srow = g * CAP + mb * 128 + wm * 64 + i * 16 + lk * 4 + r;
            const size_t base = (size_t)srow * FDIM + nb * 128 + wn * 64 + lrow;
#pragma unroll
            for (int j = 0; j < 4; j++) {
                const float gg = accg[i][j][r];
                const float uu = accu[i][j][r];
                const float a = (gg / (1.f + __expf(-gg))) * uu;
                act[base + j * 16] = f2bf(a);
            }
        }
}

// ---------------- gemm2: out[token] += w * (act @ wo^T) ----------------
__global__ __launch_bounds__(256, 2) void gemm2_kernel(
    const unsigned short* __restrict__ act,
    const float* __restrict__ wo,
    const int* __restrict__ slot_tok, const float* __restrict__ w_slot,
    float* __restrict__ out)
{
    __shared__ __align__(16) unsigned short smem[8192]; // A:0..4095  B:4096..8191
    const int b = blockIdx.x;
    const int g = b / 80;
    const int rem = b % 80;
    const int mb = rem / 8, nb = rem % 8;
    const int e = g & 7;
    const int t = threadIdx.x;
    const int wave = t >> 6, lane = t & 63;

    const unsigned short* Asrc = act + (size_t)(g * CAP + mb * 128) * FDIM;
    const float* Bsrc = wo + (size_t)e * DDIM * FDIM + (size_t)(nb * 128) * FDIM;

    const int arow = t >> 2;
    const int acol = (t & 3) * 8;
    const int brow = t >> 3;
    const int bcol = (t & 7) * 4;

    const f32x4 fzero = {0.f, 0.f, 0.f, 0.f};
    f32x4 acc[4][4];
#pragma unroll
    for (int i = 0; i < 4; i++)
#pragma unroll
        for (int j = 0; j < 4; j++) acc[i][j] = fzero;

    const int wm = wave >> 1, wn = wave & 1;
    const int lrow = lane & 15, lk = lane >> 4;

    for (int k0 = 0; k0 < FDIM; k0 += 32) {
        __syncthreads();
        async_cp16(Asrc + (size_t)arow * FDIM + k0 + acol,        &smem[wave * 512]);
        async_cp16(Asrc + (size_t)(arow + 64) * FDIM + k0 + acol, &smem[2048 + wave * 512]);
#pragma unroll
        for (int p = 0; p < 4; p++) {
            const int r = p * 32 + brow;
            const float4 bv = *(const float4*)(Bsrc + (size_t)r * FDIM + k0 + bcol);
            uint2 bp;
            bp.x = (unsigned)f2bf(bv.x) | ((unsigned)f2bf(bv.y) << 16);
            bp.y = (unsigned)f2bf(bv.z) | ((unsigned)f2bf(bv.w) << 16);
            *(uint2*)&smem[4096 + r * 32 + bcol] = bp;
        }
        __syncthreads();
        bf16x8 af[4], bfr[4];
#pragma unroll
        for (int i = 0; i < 4; i++)
            af[i] = *(const bf16x8*)&smem[(wm * 64 + i * 16 + lrow) * 32 + lk * 8];
#pragma unroll
        for (int j = 0; j < 4; j++)
            bfr[j] = *(const bf16x8*)&smem[4096 + (wn * 64 + j * 16 + lrow) * 32 + lk * 8];
#pragma unroll
        for (int i = 0; i < 4; i++)
#pragma unroll
            for (int j = 0; j < 4; j++)
                acc[i][j] = __builtin_amdgcn_mfma_f32_16x16x32_bf16(af[i], bfr[j], acc[i][j], 0, 0, 0);
    }
    // epilogue: scatter-combine with weight, skip empty slots
#pragma unroll
    for (int i = 0; i < 4; i++)
#pragma unroll
        for (int r = 0; r < 4; r++) {
            const int srow = g * CAP + mb * 128 + wm * 64 + i * 16 + lk * 4 + r;
            const int token = slot_tok[srow];
            if (token >= 0) {
                const float w = w_slot[srow];
                const size_t obase = (size_t)token * DDIM + nb * 128 + wn * 64 + lrow;
#pragma unroll
                for (int j = 0; j < 4; j++)
                    atomicAdd(&out[obase + j * 16], acc[i][j][r] * w);
            }
        }
}

// ---------------- aux loss ----------------
__global__ void aux_kernel(const float* __restrict__ stats, float* __restrict__ out)
{
    if (threadIdx.x == 0 && blockIdx.x == 0) {
        float ps[NEXP], cn[NEXP], z = 0.f;
#pragma unroll
        for (int e = 0; e < NEXP; e++) { ps[e] = 0.f; cn[e] = 0.f; }
        for (int c = 0; c < 64; c++) {
            const float* sp = stats + c * 17;
#pragma unroll
            for (int e = 0; e < NEXP; e++) { ps[e] += sp[e]; cn[e] += sp[8 + e]; }
            z += sp[16];
        }
        float lb = 0.f;
#pragma unroll
        for (int e = 0; e < NEXP; e++)
            lb += (cn[e] / (2.f * N_TOK)) * (ps[e] / N_TOK);
        const float aux = 0.01f * 8.f * lb + 0.001f * (z / N_TOK);
        out[(size_t)N_TOK * DDIM] = aux;
    }
}

extern "C" void kernel_launch(void* const* d_in, const int* in_sizes, int n_in,
                              void* d_out, int out_size, void* d_ws, size_t ws_size,
                              hipStream_t stream)
{
    (void)in_sizes; (void)n_in; (void)ws_size;
    const float* x       = (const float*)d_in[0];
    const float* gate_w  = (const float*)d_in[1];
    const float* wi_gate = (const float*)d_in[2];
    const float* wi_up   = (const float*)d_in[3];
    const float* wo      = (const float*)d_in[4];
    float* out = (float*)d_out;
    char* ws = (char*)d_ws;

    int*            topk_idx = (int*)(ws + 0);          //  65536 B
    float*          topk_w   = (float*)(ws + 65536);    //  65536 B
    int*            slot_tok = (int*)(ws + 131072);     //  81920 B
    float*          w_slot   = (float*)(ws + 212992);   //  81920 B
    float*          stats    = (float*)(ws + 294912);   //   4352 B
    unsigned short* disp     = (unsigned short*)(ws + 299264);    // 41943040 B
    unsigned short* act      = (unsigned short*)(ws + 42242304);  // 167772160 B  (total ~210 MB)

    hipMemsetAsync(d_out, 0, (size_t)out_size * sizeof(float), stream);
    hipMemsetAsync(stats, 0, 64 * 17 * sizeof(float), stream);

    router_kernel<<<N_TOK, 256, 0, stream>>>(x, gate_w, topk_idx, topk_w, stats);
    pos_kernel<<<1, 512, 0, stream>>>(topk_idx, topk_w, slot_tok, w_slot);
    dispatch_kernel<<<NSLOT, 128, 0, stream>>>(x, slot_tok, disp);
    gemm1_kernel<<<NGROUP * 10 * 32, 256, 0, stream>>>(disp, wi_gate, wi_up, act);
    gemm2_kernel<<<NGROUP * 10 * 8, 256, 0, stream>>>(act, wo, slot_tok, w_slot, out);
    aux_kernel<<<1, 64, 0, stream>>>(stats, out);
}

// Round 2
// 1145.600 us; speedup vs baseline: 1.1830x; 1.1830x over previous
//
#include <hip/hip_runtime.h>
#include <cstdint>
#include <cstddef>

#define N_TOK 8192
#define DDIM  1024
#define FDIM  4096
#define NEXP  8
#define CAP   1280
#define MPE   2560                 // slot rows per expert (k=0 half then k=1 half)
#define NSLOT (NEXP * MPE)         // 20480

typedef __attribute__((ext_vector_type(8))) __bf16 bf16x8;
typedef __attribute__((ext_vector_type(4))) float  f32x4;

__device__ __forceinline__ unsigned short f2bf(float f) {
    unsigned int u = __float_as_uint(f);
    u += 0x7fffu + ((u >> 16) & 1u);   // RNE (finite inputs)
    return (unsigned short)(u >> 16);
}
__device__ __forceinline__ float bf2f(unsigned short s) {
    unsigned int u = ((unsigned int)s) << 16;
    return __uint_as_float(u);
}

__device__ __forceinline__ void async_cp16(const void* g, void* l) {
    __builtin_amdgcn_global_load_lds(
        (const __attribute__((address_space(1))) unsigned int*)g,
        (__attribute__((address_space(3))) unsigned int*)l, 16, 0, 0);
}

// ---------------- weight pre-convert: fp32 -> bf16 ----------------
// wcomb[e][8192][1024]: row r -> fb=r>>7, half=(r>>6)&1, fi=r&63, feature f=fb*64+fi
// half 0 = wi_gate row f, half 1 = wi_up row f.
__global__ __launch_bounds__(256) void convert_wi_kernel(
    const float* __restrict__ wi_gate, const float* __restrict__ wi_up,
    unsigned short* __restrict__ wcomb)
{
    const int idx = blockIdx.x * 256 + threadIdx.x;   // 8M threads, 8 elems each
    const int d8 = idx & 127;
    const int r  = (idx >> 7) & 8191;
    const int e  = idx >> 20;
    const int f  = (r >> 7) * 64 + (r & 63);
    const float* src = (((r >> 6) & 1) ? wi_up : wi_gate)
                       + ((size_t)(e * FDIM + f) * DDIM + d8 * 8);
    const float4 a = ((const float4*)src)[0];
    const float4 b = ((const float4*)src)[1];
    uint4 o;
    o.x = (unsigned)f2bf(a.x) | ((unsigned)f2bf(a.y) << 16);
    o.y = (unsigned)f2bf(a.z) | ((unsigned)f2bf(a.w) << 16);
    o.z = (unsigned)f2bf(b.x) | ((unsigned)f2bf(b.y) << 16);
    o.w = (unsigned)f2bf(b.z) | ((unsigned)f2bf(b.w) << 16);
    *(uint4*)(wcomb + (size_t)idx * 8) = o;
}

__global__ __launch_bounds__(256) void convert_wo_kernel(
    const float* __restrict__ wo, unsigned short* __restrict__ wo_bf)
{
    const int idx = blockIdx.x * 256 + threadIdx.x;   // 4M threads, 8 elems each
    const float4 a = ((const float4*)(wo + (size_t)idx * 8))[0];
    const float4 b = ((const float4*)(wo + (size_t)idx * 8))[1];
    uint4 o;
    o.x = (unsigned)f2bf(a.x) | ((unsigned)f2bf(a.y) << 16);
    o.y = (unsigned)f2bf(a.z) | ((unsigned)f2bf(a.w) << 16);
    o.z = (unsigned)f2bf(b.x) | ((unsigned)f2bf(b.y) << 16);
    o.w = (unsigned)f2bf(b.z) | ((unsigned)f2bf(b.w) << 16);
    *(uint4*)(wo_bf + (size_t)idx * 8) = o;
}

// ---------------- router: logits, softmax, top2, stats ----------------
__global__ __launch_bounds__(256) void router_kernel(
    const float* __restrict__ x, const float* __restrict__ gate_w,
    int* __restrict__ topk_idx, float* __restrict__ topk_w,
    float* __restrict__ stats)
{
    __shared__ float red[256][9];
    const int n = blockIdx.x;
    const int t = threadIdx.x;
    const float4 xv = *(const float4*)(x + (size_t)n * DDIM + t * 4);
#pragma unroll
    for (int e = 0; e < NEXP; e++) {
        const float4 gv = *(const float4*)(gate_w + (size_t)e * DDIM + t * 4);
        red[t][e] = xv.x * gv.x + xv.y * gv.y + xv.z * gv.z + xv.w * gv.w;
    }
    __syncthreads();
    for (int s = 128; s > 0; s >>= 1) {
        if (t < s) {
#pragma unroll
            for (int e = 0; e < NEXP; e++) red[t][e] += red[t + s][e];
        }
        __syncthreads();
    }
    if (t == 0) {
        float l[NEXP], p[NEXP];
        float m = -1e30f;
#pragma unroll
        for (int e = 0; e < NEXP; e++) { l[e] = red[0][e]; m = fmaxf(m, l[e]); }
        float sum = 0.f;
#pragma unroll
        for (int e = 0; e < NEXP; e++) { p[e] = expf(l[e] - m); sum += p[e]; }
        const float inv = 1.f / sum;
#pragma unroll
        for (int e = 0; e < NEXP; e++) p[e] *= inv;
        const float lse = m + logf(sum);
        int e1 = 0; float p1 = p[0];
#pragma unroll
        for (int e = 1; e < NEXP; e++) if (p[e] > p1) { p1 = p[e]; e1 = e; }
        int e2 = -1; float p2 = -1.f;
#pragma unroll
        for (int e = 0; e < NEXP; e++) if (e != e1 && p[e] > p2) { p2 = p[e]; e2 = e; }
        const float wsum = p1 + p2;
        topk_idx[n * 2 + 0] = e1; topk_idx[n * 2 + 1] = e2;
        topk_w[n * 2 + 0] = p1 / wsum; topk_w[n * 2 + 1] = p2 / wsum;
        float* sp = stats + (n & 63) * 17;
#pragma unroll
        for (int e = 0; e < NEXP; e++) atomicAdd(sp + e, p[e]);
        atomicAdd(sp + 8 + e1, 1.f);
        atomicAdd(sp + 8 + e2, 1.f);
        atomicAdd(sp + 16, lse * lse);
    }
}

// ---------------- positions: first-come cumsum per (k,e), capacity drop ----------------
// slot layout: slot = (e*2 + kk)*CAP + p   (e-major -> expert rows contiguous)
__global__ __launch_bounds__(512) void pos_kernel(
    const int* __restrict__ topk_idx, const float* __restrict__ topk_w,
    int* __restrict__ slot_tok, float* __restrict__ w_slot, int* __restrict__ gcnt)
{
    __shared__ int cnt[2][NEXP][256];
    const int t = threadIdx.x;
    for (int i = t; i < NSLOT; i += 512) { slot_tok[i] = -1; w_slot[i] = 0.f; }
    const int kk = t >> 8;
    const int c  = t & 255;
    int lc[NEXP];
#pragma unroll
    for (int e = 0; e < NEXP; e++) lc[e] = 0;
    const int base_n = c * 32;
    for (int i = 0; i < 32; i++) lc[topk_idx[(base_n + i) * 2 + kk]]++;
#pragma unroll
    for (int e = 0; e < NEXP; e++) cnt[kk][e][c] = lc[e];
    __syncthreads();
    if (t < 16) {                      // 16 serial exclusive scans of 256 chunks
        const int k2 = t >> 3, e = t & 7;
        int run = 0;
        for (int c2 = 0; c2 < 256; c2++) { int v = cnt[k2][e][c2]; cnt[k2][e][c2] = run; run += v; }
        gcnt[e * 2 + k2] = run < CAP ? run : CAP;
    }
    __syncthreads();
    int run[NEXP];
#pragma unroll
    for (int e = 0; e < NEXP; e++) run[e] = cnt[kk][e][c];
    for (int i = 0; i < 32; i++) {
        const int n = base_n + i;
        const int e = topk_idx[n * 2 + kk];
        const int p = run[e]++;
        if (p < CAP) {
            const int slot = (e * 2 + kk) * CAP + p;
            slot_tok[slot] = n;
            w_slot[slot] = topk_w[n * 2 + kk];
        }
    }
}

// ---------------- dispatch: gather x rows -> bf16 disp ----------------
__global__ __launch_bounds__(128) void dispatch_kernel(
    const float* __restrict__ x, const int* __restrict__ slot_tok,
    unsigned short* __restrict__ disp)
{
    const int slot = blockIdx.x;
    const int t = threadIdx.x;
    const int token = slot_tok[slot];
    uint4 o = make_uint4(0u, 0u, 0u, 0u);
    if (token >= 0) {
        const float4* src = (const float4*)(x + (size_t)token * DDIM + t * 8);
        const float4 a = src[0];
        const float4 b = src[1];
        o.x = (unsigned)f2bf(a.x) | ((unsigned)f2bf(a.y) << 16);
        o.y = (unsigned)f2bf(a.z) | ((unsigned)f2bf(a.w) << 16);
        o.z = (unsigned)f2bf(b.x) | ((unsigned)f2bf(b.y) << 16);
        o.w = (unsigned)f2bf(b.z) | ((unsigned)f2bf(b.w) << 16);
    }
    *(uint4*)(disp + (size_t)slot * DDIM + t * 8) = o;
}

// ---------------- gemm1: act = bf16( silu(disp@Wg^T) * (disp@Wu^T) ) ----------------
// m97 structure: 128x128 tile over interleaved N=8192, BK=32, pure DMA staging,
// 64 AGPR acc, silu*up fused via LDS exchange (wn=0 waves = gate, wn=1 = up).
__global__ __launch_bounds__(256, 3) void gemm1_kernel(
    const unsigned short* __restrict__ disp,
    const unsigned short* __restrict__ wcomb,
    const int* __restrict__ gcnt,
    unsigned short* __restrict__ act)
{
    __shared__ __align__(16) unsigned short smem[8192]; // A:0..4095 B:4096..8191; reused as exch[128][64]
    const int b = blockIdx.x;
    const int e   = b / 1280;          // 20 mb * 64 nb
    const int rem = b % 1280;
    const int mb = rem / 64, nb = rem % 64;
    const int kk = mb / 10;
    if ((mb % 10) * 128 >= gcnt[e * 2 + kk]) return;   // fully-empty tile

    const int t = threadIdx.x;
    const int wave = t >> 6, lane = t & 63;
    const unsigned short* Asrc = disp  + (size_t)(e * MPE + mb * 128) * DDIM;
    const unsigned short* Bsrc = wcomb + (size_t)e * 8192 * DDIM + (size_t)(nb * 128) * DDIM;

    const int arow = t >> 2;           // 0..63
    const int acol = (t & 3) * 8;

    const f32x4 fzero = {0.f, 0.f, 0.f, 0.f};
    f32x4 acc[4][4];
#pragma unroll
    for (int i = 0; i < 4; i++)
#pragma unroll
        for (int j = 0; j < 4; j++) acc[i][j] = fzero;

    const int wm = wave >> 1, wn = wave & 1;
    const int lrow = lane & 15, lk = lane >> 4;

    for (int k0 = 0; k0 < DDIM; k0 += 32) {
        __syncthreads();
        async_cp16(Asrc + (size_t)arow * DDIM + k0 + acol,        &smem[wave * 512]);
        async_cp16(Asrc + (size_t)(arow + 64) * DDIM + k0 + acol, &smem[2048 + wave * 512]);
        async_cp16(Bsrc + (size_t)arow * DDIM + k0 + acol,        &smem[4096 + wave * 512]);
        async_cp16(Bsrc + (size_t)(arow + 64) * DDIM + k0 + acol, &smem[6144 + wave * 512]);
        __syncthreads();
        bf16x8 af[4], bfr[4];
#pragma unroll
        for (int i = 0; i < 4; i++)
            af[i] = *(const bf16x8*)&smem[(wm * 64 + i * 16 + lrow) * 32 + lk * 8];
#pragma unroll
        for (int j = 0; j < 4; j++)
            bfr[j] = *(const bf16x8*)&smem[4096 + (wn * 64 + j * 16 + lrow) * 32 + lk * 8];
#pragma unroll
        for (int i = 0; i < 4; i++)
#pragma unroll
            for (int j = 0; j < 4; j++)
                acc[i][j] = __builtin_amdgcn_mfma_f32_16x16x32_bf16(af[i], bfr[j], acc[i][j], 0, 0, 0);
    }

    // epilogue: exchange gate through LDS, up-waves compute silu(g)*u -> act bf16
    __syncthreads();
    if (wn == 0) {
#pragma unroll
        for (int i = 0; i < 4; i++)
#pragma unroll
            for (int j = 0; j < 4; j++)
#pragma unroll
                for (int r = 0; r < 4; r++)
                    smem[(wm * 64 + i * 16 + lk * 4 + r) * 64 + j * 16 + lrow] = f2bf(acc[i][j][r]);
    }
    __syncthreads();
    if (wn == 1) {
#pragma unroll
        for (int i = 0; i < 4; i++)
#pragma unroll
            for (int r = 0; r < 4; r++) {
                const int m = wm * 64 + i * 16 + lk * 4 + r;
                const size_t base = (size_t)(e * MPE + mb * 128 + m) * FDIM + nb * 64;
#pragma unroll
                for (int j = 0; j < 4; j++) {
                    const float g = bf2f(smem[m * 64 + j * 16 + lrow]);
                    const float u = acc[i][j][r];
                    const float a = (g / (1.f + __expf(-g))) * u;
                    act[base + j * 16 + lrow] = f2bf(a);
                }
            }
    }
}

// ---------------- gemm2: out[token] += w * (act @ wo^T) ----------------
__global__ __launch_bounds__(256, 3) void gemm2_kernel(
    const unsigned short* __restrict__ act,
    const unsigned short* __restrict__ wo_bf,
    const int* __restrict__ slot_tok, const float* __restrict__ w_slot,
    const int* __restrict__ gcnt,
    float* __restrict__ out)
{
    __shared__ __align__(16) unsigned short smem[8192]; // A:0..4095  B:4096..8191
    const int b = blockIdx.x;
    const int e   = b / 160;           // 20 mb * 8 nb
    const int rem = b % 160;
    const int mb = rem / 8, nb = rem % 8;
    const int kk = mb / 10;
    if ((mb % 10) * 128 >= gcnt[e * 2 + kk]) return;   // fully-empty tile

    const int t = threadIdx.x;
    const int wave = t >> 6, lane = t & 63;
    const unsigned short* Asrc = act   + (size_t)(e * MPE + mb * 128) * FDIM;
    const unsigned short* Bsrc = wo_bf + (size_t)e * DDIM * FDIM + (size_t)(nb * 128) * FDIM;

    const int arow = t >> 2;
    const int acol = (t & 3) * 8;

    const f32x4 fzero = {0.f, 0.f, 0.f, 0.f};
    f32x4 acc[4][4];
#pragma unroll
    for (int i = 0; i < 4; i++)
#pragma unroll
        for (int j = 0; j < 4; j++) acc[i][j] = fzero;

    const int wm = wave >> 1, wn = wave & 1;
    const int lrow = lane & 15, lk = lane >> 4;

    for (int k0 = 0; k0 < FDIM; k0 += 32) {
        __syncthreads();
        async_cp16(Asrc + (size_t)arow * FDIM + k0 + acol,        &smem[wave * 512]);
        async_cp16(Asrc + (size_t)(arow + 64) * FDIM + k0 + acol, &smem[2048 + wave * 512]);
        async_cp16(Bsrc + (size_t)arow * FDIM + k0 + acol,        &smem[4096 + wave * 512]);
        async_cp16(Bsrc + (size_t)(arow + 64) * FDIM + k0 + acol, &smem[6144 + wave * 512]);
        __syncthreads();
        bf16x8 af[4], bfr[4];
#pragma unroll
        for (int i = 0; i < 4; i++)
            af[i] = *(const bf16x8*)&smem[(wm * 64 + i * 16 + lrow) * 32 + lk * 8];
#pragma unroll
        for (int j = 0; j < 4; j++)
            bfr[j] = *(const bf16x8*)&smem[4096 + (wn * 64 + j * 16 + lrow) * 32 + lk * 8];
#pragma unroll
        for (int i = 0; i < 4; i++)
#pragma unroll
            for (int j = 0; j < 4; j++)
                acc[i][j] = __builtin_amdgcn_mfma_f32_16x16x32_bf16(af[i], bfr[j], acc[i][j], 0, 0, 0);
    }
    // epilogue: scatter-combine with weight, skip empty slots
#pragma unroll
    for (int i = 0; i < 4; i++)
#pragma unroll
        for (int r = 0; r < 4; r++) {
            const int srow = e * MPE + mb * 128 + wm * 64 + i * 16 + lk * 4 + r;
            const int token = slot_tok[srow];
            if (token >= 0) {
                const float w = w_slot[srow];
                const size_t obase = (size_t)token * DDIM + nb * 128 + wn * 64 + lrow;
#pragma unroll
                for (int j = 0; j < 4; j++)
                    atomicAdd(&out[obase + j * 16], acc[i][j][r] * w);
            }
        }
}

// ---------------- aux loss ----------------
__global__ void aux_kernel(const float* __restrict__ stats, float* __restrict__ out)
{
    if (threadIdx.x == 0 && blockIdx.x == 0) {
        float ps[NEXP], cn[NEXP], z = 0.f;
#pragma unroll
        for (int e = 0; e < NEXP; e++) { ps[e] = 0.f; cn[e] = 0.f; }
        for (int c = 0; c < 64; c++) {
            const float* sp = stats + c * 17;
#pragma unroll
            for (int e = 0; e < NEXP; e++) { ps[e] += sp[e]; cn[e] += sp[8 + e]; }
            z += sp[16];
        }
        float lb = 0.f;
#pragma unroll
        for (int e = 0; e < NEXP; e++)
            lb += (cn[e] / (2.f * N_TOK)) * (ps[e] / N_TOK);
        const float aux = 0.01f * 8.f * lb + 0.001f * (z / N_TOK);
        out[(size_t)N_TOK * DDIM] = aux;
    }
}

extern "C" void kernel_launch(void* const* d_in, const int* in_sizes, int n_in,
                              void* d_out, int out_size, void* d_ws, size_t ws_size,
                              hipStream_t stream)
{
    (void)in_sizes; (void)n_in; (void)ws_size;
    const float* x       = (const float*)d_in[0];
    const float* gate_w  = (const float*)d_in[1];
    const float* wi_gate = (const float*)d_in[2];
    const float* wi_up   = (const float*)d_in[3];
    const float* wo      = (const float*)d_in[4];
    float* out = (float*)d_out;
    char* ws = (char*)d_ws;

    // workspace layout (~393 MB)
    int*            topk_idx = (int*)(ws + 0);          //  65536 B
    float*          topk_w   = (float*)(ws + 65536);    //  65536 B
    int*            slot_tok = (int*)(ws + 131072);     //  81920 B
    float*          w_slot   = (float*)(ws + 212992);   //  81920 B
    float*          stats    = (float*)(ws + 294912);   //   4352 B
    int*            gcnt     = (int*)(ws + 299264);     //     64 B
    unsigned short* disp     = (unsigned short*)(ws + 524288);     //  41943040 B
    unsigned short* act      = (unsigned short*)(ws + 42467328);   // 167772160 B
    unsigned short* wcomb    = (unsigned short*)(ws + 210239488);  // 134217728 B
    unsigned short* wo_bf    = (unsigned short*)(ws + 344457216);  //  67108864 B  -> end 411566080

    hipMemsetAsync(d_out, 0, (size_t)out_size * sizeof(float), stream);
    hipMemsetAsync(stats, 0, 64 * 17 * sizeof(float), stream);

    convert_wi_kernel<<<32768, 256, 0, stream>>>(wi_gate, wi_up, wcomb);
    convert_wo_kernel<<<16384, 256, 0, stream>>>(wo, wo_bf);
    router_kernel<<<N_TOK, 256, 0, stream>>>(x, gate_w, topk_idx, topk_w, stats);
    pos_kernel<<<1, 512, 0, stream>>>(topk_idx, topk_w, slot_tok, w_slot, gcnt);
    dispatch_kernel<<<NSLOT, 128, 0, stream>>>(x, slot_tok, disp);
    gemm1_kernel<<<NEXP * 20 * 64, 256, 0, stream>>>(disp, wcomb, gcnt, act);
    gemm2_kernel<<<NEXP * 20 * 8, 256, 0, stream>>>(act, wo_bf, slot_tok, w_slot, gcnt, out);
    aux_kernel<<<1, 64, 0, stream>>>(stats, out);
}

// Round 3
// 1112.299 us; speedup vs baseline: 1.2184x; 1.0299x over previous
//
#include <hip/hip_runtime.h>
#include <cstdint>
#include <cstddef>

#define N_TOK 8192
#define DDIM  1024
#define FDIM  4096
#define NEXP  8
#define CAP   1280
#define MPE   2560                 // slot rows per expert (k=0 half then k=1 half)
#define NSLOT (NEXP * MPE)         // 20480

typedef __attribute__((ext_vector_type(8))) __bf16 bf16x8;
typedef __attribute__((ext_vector_type(4))) float  f32x4;

__device__ __forceinline__ unsigned short f2bf(float f) {
    unsigned int u = __float_as_uint(f);
    u += 0x7fffu + ((u >> 16) & 1u);   // RNE (finite inputs)
    return (unsigned short)(u >> 16);
}
__device__ __forceinline__ float bf2f(unsigned short s) {
    return __uint_as_float(((unsigned int)s) << 16);
}

__device__ __forceinline__ void async_cp16(const void* g, void* l) {
    __builtin_amdgcn_global_load_lds(
        (const __attribute__((address_space(1))) unsigned int*)g,
        (__attribute__((address_space(3))) unsigned int*)l, 16, 0, 0);
}

// ---------------- weight pre-convert: fp32 -> bf16 ----------------
// wcomb[e][8192][1024]: row r -> fb=r>>7, half=(r>>6)&1, fi=r&63, feature f=fb*64+fi
__global__ __launch_bounds__(256) void convert_wi_kernel(
    const float* __restrict__ wi_gate, const float* __restrict__ wi_up,
    unsigned short* __restrict__ wcomb)
{
    const int idx = blockIdx.x * 256 + threadIdx.x;   // 8M threads, 8 elems each
    const int d8 = idx & 127;
    const int r  = (idx >> 7) & 8191;
    const int e  = idx >> 20;
    const int f  = (r >> 7) * 64 + (r & 63);
    const float* src = (((r >> 6) & 1) ? wi_up : wi_gate)
                       + ((size_t)(e * FDIM + f) * DDIM + d8 * 8);
    const float4 a = ((const float4*)src)[0];
    const float4 b = ((const float4*)src)[1];
    uint4 o;
    o.x = (unsigned)f2bf(a.x) | ((unsigned)f2bf(a.y) << 16);
    o.y = (unsigned)f2bf(a.z) | ((unsigned)f2bf(a.w) << 16);
    o.z = (unsigned)f2bf(b.x) | ((unsigned)f2bf(b.y) << 16);
    o.w = (unsigned)f2bf(b.z) | ((unsigned)f2bf(b.w) << 16);
    *(uint4*)(wcomb + (size_t)idx * 8) = o;
}

__global__ __launch_bounds__(256) void convert_wo_kernel(
    const float* __restrict__ wo, unsigned short* __restrict__ wo_bf)
{
    const int idx = blockIdx.x * 256 + threadIdx.x;   // 4M threads, 8 elems each
    const float4 a = ((const float4*)(wo + (size_t)idx * 8))[0];
    const float4 b = ((const float4*)(wo + (size_t)idx * 8))[1];
    uint4 o;
    o.x = (unsigned)f2bf(a.x) | ((unsigned)f2bf(a.y) << 16);
    o.y = (unsigned)f2bf(a.z) | ((unsigned)f2bf(a.w) << 16);
    o.z = (unsigned)f2bf(b.x) | ((unsigned)f2bf(b.y) << 16);
    o.w = (unsigned)f2bf(b.z) | ((unsigned)f2bf(b.w) << 16);
    *(uint4*)(wo_bf + (size_t)idx * 8) = o;
}

// ---------------- router: wave-per-token, shuffle reduce ----------------
__global__ __launch_bounds__(256) void router_kernel(
    const float* __restrict__ x, const float* __restrict__ gate_w,
    int* __restrict__ topk_idx, float* __restrict__ topk_w,
    float* __restrict__ stats)
{
    const int wave = threadIdx.x >> 6, lane = threadIdx.x & 63;
    const int n = blockIdx.x * 4 + wave;
    const float4* xp = (const float4*)(x + (size_t)n * DDIM + lane * 16);
    float4 xv[4];
#pragma unroll
    for (int i = 0; i < 4; i++) xv[i] = xp[i];
    float part[NEXP];
#pragma unroll
    for (int e = 0; e < NEXP; e++) {
        const float4* gp = (const float4*)(gate_w + (size_t)e * DDIM + lane * 16);
        float s = 0.f;
#pragma unroll
        for (int i = 0; i < 4; i++) {
            const float4 g = gp[i];
            s += xv[i].x * g.x + xv[i].y * g.y + xv[i].z * g.z + xv[i].w * g.w;
        }
        part[e] = s;
    }
#pragma unroll
    for (int off = 32; off > 0; off >>= 1)
#pragma unroll
        for (int e = 0; e < NEXP; e++) part[e] += __shfl_down(part[e], off);
    if (lane == 0) {
        float p[NEXP];
        float m = -1e30f;
#pragma unroll
        for (int e = 0; e < NEXP; e++) m = fmaxf(m, part[e]);
        float sum = 0.f;
#pragma unroll
        for (int e = 0; e < NEXP; e++) { p[e] = __expf(part[e] - m); sum += p[e]; }
        const float inv = 1.f / sum;
#pragma unroll
        for (int e = 0; e < NEXP; e++) p[e] *= inv;
        const float lse = m + __logf(sum);
        int e1 = 0; float p1 = p[0];
#pragma unroll
        for (int e = 1; e < NEXP; e++) if (p[e] > p1) { p1 = p[e]; e1 = e; }
        int e2 = -1; float p2 = -1.f;
#pragma unroll
        for (int e = 0; e < NEXP; e++) if (e != e1 && p[e] > p2) { p2 = p[e]; e2 = e; }
        const float wsum = p1 + p2;
        topk_idx[n * 2 + 0] = e1; topk_idx[n * 2 + 1] = e2;
        topk_w[n * 2 + 0] = p1 / wsum; topk_w[n * 2 + 1] = p2 / wsum;
        float* sp = stats + (n & 63) * 17;
#pragma unroll
        for (int e = 0; e < NEXP; e++) atomicAdd(sp + e, p[e]);
        atomicAdd(sp + 8 + e1, 1.f);
        atomicAdd(sp + 8 + e2, 1.f);
        atomicAdd(sp + 16, lse * lse);
    }
}

// ---------------- positions: first-come cumsum per (k,e), capacity drop ----------------
// slot layout: slot = (e*2 + kk)*CAP + p
__global__ __launch_bounds__(512) void pos_kernel(
    const int* __restrict__ topk_idx, const float* __restrict__ topk_w,
    int* __restrict__ slot_tok, int* __restrict__ tok2slot, int* __restrict__ gcnt)
{
    __shared__ int cnt[2][NEXP][256];
    const int t = threadIdx.x;
    for (int i = t; i < NSLOT; i += 512) slot_tok[i] = -1;
    const int kk = t >> 8;
    const int c  = t & 255;
    int lc[NEXP];
#pragma unroll
    for (int e = 0; e < NEXP; e++) lc[e] = 0;
    const int base_n = c * 32;
    for (int i = 0; i < 32; i++) lc[topk_idx[(base_n + i) * 2 + kk]]++;
#pragma unroll
    for (int e = 0; e < NEXP; e++) cnt[kk][e][c] = lc[e];
    __syncthreads();
    if (t < 16) {                      // 16 serial exclusive scans of 256 chunks
        const int k2 = t >> 3, e = t & 7;
        int run = 0;
        for (int c2 = 0; c2 < 256; c2++) { int v = cnt[k2][e][c2]; cnt[k2][e][c2] = run; run += v; }
        gcnt[e * 2 + k2] = run < CAP ? run : CAP;
    }
    __syncthreads();
    int run[NEXP];
#pragma unroll
    for (int e = 0; e < NEXP; e++) run[e] = cnt[kk][e][c];
    for (int i = 0; i < 32; i++) {
        const int n = base_n + i;
        const int e = topk_idx[n * 2 + kk];
        const int p = run[e]++;
        if (p < CAP) {
            const int slot = (e * 2 + kk) * CAP + p;
            slot_tok[slot] = n;
            tok2slot[n * 2 + kk] = slot;
        } else {
            tok2slot[n * 2 + kk] = -1;
        }
    }
}

// ---------------- dispatch: gather x rows -> bf16 disp ----------------
__global__ __launch_bounds__(128) void dispatch_kernel(
    const float* __restrict__ x, const int* __restrict__ slot_tok,
    unsigned short* __restrict__ disp)
{
    const int slot = blockIdx.x;
    const int t = threadIdx.x;
    const int token = slot_tok[slot];
    uint4 o = make_uint4(0u, 0u, 0u, 0u);
    if (token >= 0) {
        const float4* src = (const float4*)(x + (size_t)token * DDIM + t * 8);
        const float4 a = src[0];
        const float4 b = src[1];
        o.x = (unsigned)f2bf(a.x) | ((unsigned)f2bf(a.y) << 16);
        o.y = (unsigned)f2bf(a.z) | ((unsigned)f2bf(a.w) << 16);
        o.z = (unsigned)f2bf(b.x) | ((unsigned)f2bf(b.y) << 16);
        o.w = (unsigned)f2bf(b.z) | ((unsigned)f2bf(b.w) << 16);
    }
    *(uint4*)(disp + (size_t)slot * DDIM + t * 8) = o;
}

// ---------------- gemm1: act = bf16( silu(disp@Wg^T) * (disp@Wu^T) ) ----------------
// 128x128 tile, BK=32, DMA staging with XOR-swizzled 16B chunks (kills 8-way
// ds_read_b128 bank conflicts), silu*up fused via padded LDS exchange.
__global__ __launch_bounds__(256, 3) void gemm1_kernel(
    const unsigned short* __restrict__ disp,
    const unsigned short* __restrict__ wcomb,
    const int* __restrict__ gcnt,
    unsigned short* __restrict__ act)
{
    __shared__ __align__(16) unsigned short smem[8704]; // GEMM: A 0..4095, B 4096..8191; epilogue: exch[128][68]
    const int b = blockIdx.x;
    const int e   = b / 1280;          // 20 mb * 64 nb
    const int rem = b % 1280;
    const int mb = rem / 64, nb = rem % 64;
    const int kk = mb / 10;
    if ((mb % 10) * 128 >= gcnt[e * 2 + kk]) return;   // fully-empty tile

    const int t = threadIdx.x;
    const int wave = t >> 6, lane = t & 63;
    const unsigned short* Asrc = disp  + (size_t)(e * MPE + mb * 128) * DDIM;
    const unsigned short* Bsrc = wcomb + (size_t)e * 8192 * DDIM + (size_t)(nb * 128) * DDIM;

    const int arow = t >> 2;           // 0..63
    const int acol = (((t & 3) ^ ((arow >> 1) & 3)) * 8);   // swizzled chunk

    const f32x4 fzero = {0.f, 0.f, 0.f, 0.f};
    f32x4 acc[4][4];
#pragma unroll
    for (int i = 0; i < 4; i++)
#pragma unroll
        for (int j = 0; j < 4; j++) acc[i][j] = fzero;

    const int wm = wave >> 1, wn = wave & 1;
    const int lrow = lane & 15, lk = lane >> 4;
    const int lkx = (lk ^ ((lrow >> 1) & 3)) * 8;           // read-side swizzle

    for (int k0 = 0; k0 < DDIM; k0 += 32) {
        __syncthreads();
        async_cp16(Asrc + (size_t)arow * DDIM + k0 + acol,        &smem[wave * 512]);
        async_cp16(Asrc + (size_t)(arow + 64) * DDIM + k0 + acol, &smem[2048 + wave * 512]);
        async_cp16(Bsrc + (size_t)arow * DDIM + k0 + acol,        &smem[4096 + wave * 512]);
        async_cp16(Bsrc + (size_t)(arow + 64) * DDIM + k0 + acol, &smem[6144 + wave * 512]);
        __syncthreads();
        bf16x8 af[4], bfr[4];
#pragma unroll
        for (int i = 0; i < 4; i++)
            af[i] = *(const bf16x8*)&smem[(wm * 64 + i * 16 + lrow) * 32 + lkx];
#pragma unroll
        for (int j = 0; j < 4; j++)
            bfr[j] = *(const bf16x8*)&smem[4096 + (wn * 64 + j * 16 + lrow) * 32 + lkx];
#pragma unroll
        for (int i = 0; i < 4; i++)
#pragma unroll
            for (int j = 0; j < 4; j++)
                acc[i][j] = __builtin_amdgcn_mfma_f32_16x16x32_bf16(af[i], bfr[j], acc[i][j], 0, 0, 0);
    }

    // epilogue: exchange gate through LDS (68-short row pitch -> conflict-free),
    // up-waves compute silu(g)*u -> act bf16
    __syncthreads();
    if (wn == 0) {
#pragma unroll
        for (int i = 0; i < 4; i++)
#pragma unroll
            for (int j = 0; j < 4; j++)
#pragma unroll
                for (int r = 0; r < 4; r++)
                    smem[(wm * 64 + i * 16 + lk * 4 + r) * 68 + j * 16 + lrow] = f2bf(acc[i][j][r]);
    }
    __syncthreads();
    if (wn == 1) {
#pragma unroll
        for (int i = 0; i < 4; i++)
#pragma unroll
            for (int r = 0; r < 4; r++) {
                const int m = wm * 64 + i * 16 + lk * 4 + r;
                const size_t base = (size_t)(e * MPE + mb * 128 + m) * FDIM + nb * 64;
#pragma unroll
                for (int j = 0; j < 4; j++) {
                    const float g = bf2f(smem[m * 68 + j * 16 + lrow]);
                    const float u = acc[i][j][r];
                    const float a = (g / (1.f + __expf(-g))) * u;
                    act[base + j * 16 + lrow] = f2bf(a);
                }
            }
    }
}

// ---------------- gemm2: eout[slot] = bf16(act @ wo^T), no atomics ----------------
__global__ __launch_bounds__(256, 3) void gemm2_kernel(
    const unsigned short* __restrict__ act,
    const unsigned short* __restrict__ wo_bf,
    const int* __restrict__ gcnt,
    unsigned short* __restrict__ eout)
{
    __shared__ __align__(16) unsigned short smem[8192]; // A:0..4095  B:4096..8191
    const int b = blockIdx.x;
    const int e   = b / 160;           // 20 mb * 8 nb
    const int rem = b % 160;
    const int mb = rem / 8, nb = rem % 8;
    const int kk = mb / 10;
    if ((mb % 10) * 128 >= gcnt[e * 2 + kk]) return;   // fully-empty tile

    const int t = threadIdx.x;
    const int wave = t >> 6, lane = t & 63;
    const unsigned short* Asrc = act   + (size_t)(e * MPE + mb * 128) * FDIM;
    const unsigned short* Bsrc = wo_bf + (size_t)e * DDIM * FDIM + (size_t)(nb * 128) * FDIM;

    const int arow = t >> 2;
    const int acol = (((t & 3) ^ ((arow >> 1) & 3)) * 8);

    const f32x4 fzero = {0.f, 0.f, 0.f, 0.f};
    f32x4 acc[4][4];
#pragma unroll
    for (int i = 0; i < 4; i++)
#pragma unroll
        for (int j = 0; j < 4; j++) acc[i][j] = fzero;

    const int wm = wave >> 1, wn = wave & 1;
    const int lrow = lane & 15, lk = lane >> 4;
    const int lkx = (lk ^ ((lrow >> 1) & 3)) * 8;

    for (int k0 = 0; k0 < FDIM; k0 += 32) {
        __syncthreads();
        async_cp16(Asrc + (size_t)arow * FDIM + k0 + acol,        &smem[wave * 512]);
        async_cp16(Asrc + (size_t)(arow + 64) * FDIM + k0 + acol, &smem[2048 + wave * 512]);
        async_cp16(Bsrc + (size_t)arow * FDIM + k0 + acol,        &smem[4096 + wave * 512]);
        async_cp16(Bsrc + (size_t)(arow + 64) * FDIM + k0 + acol, &smem[6144 + wave * 512]);
        __syncthreads();
        bf16x8 af[4], bfr[4];
#pragma unroll
        for (int i = 0; i < 4; i++)
            af[i] = *(const bf16x8*)&smem[(wm * 64 + i * 16 + lrow) * 32 + lkx];
#pragma unroll
        for (int j = 0; j < 4; j++)
            bfr[j] = *(const bf16x8*)&smem[4096 + (wn * 64 + j * 16 + lrow) * 32 + lkx];
#pragma unroll
        for (int i = 0; i < 4; i++)
#pragma unroll
            for (int j = 0; j < 4; j++)
                acc[i][j] = __builtin_amdgcn_mfma_f32_16x16x32_bf16(af[i], bfr[j], acc[i][j], 0, 0, 0);
    }
    // epilogue: plain bf16 stores to slot-major eout
#pragma unroll
    for (int i = 0; i < 4; i++)
#pragma unroll
        for (int r = 0; r < 4; r++) {
            const int srow = e * MPE + mb * 128 + wm * 64 + i * 16 + lk * 4 + r;
            const size_t obase = (size_t)srow * DDIM + nb * 128 + wn * 64;
#pragma unroll
            for (int j = 0; j < 4; j++)
                eout[obase + j * 16 + lrow] = f2bf(acc[i][j][r]);
        }
}

// ---------------- combine: out[n] = w0*eout[s0] + w1*eout[s1] ----------------
__global__ __launch_bounds__(256) void combine_kernel(
    const unsigned short* __restrict__ eout,
    const int* __restrict__ tok2slot, const float* __restrict__ topk_w,
    float* __restrict__ out)
{
    const int n = blockIdx.x;
    const int t = threadIdx.x;
    const int s0 = tok2slot[n * 2 + 0], s1 = tok2slot[n * 2 + 1];
    const float w0 = (s0 >= 0) ? topk_w[n * 2 + 0] : 0.f;
    const float w1 = (s1 >= 0) ? topk_w[n * 2 + 1] : 0.f;
    const int a0 = (s0 >= 0) ? s0 : 0;
    const int a1 = (s1 >= 0) ? s1 : 0;
    const uint2 p0 = *(const uint2*)(eout + (size_t)a0 * DDIM + t * 4);
    const uint2 p1 = *(const uint2*)(eout + (size_t)a1 * DDIM + t * 4);
    float4 o;
    o.x = w0 * bf2f((unsigned short)(p0.x & 0xffff)) + w1 * bf2f((unsigned short)(p1.x & 0xffff));
    o.y = w0 * bf2f((unsigned short)(p0.x >> 16))    + w1 * bf2f((unsigned short)(p1.x >> 16));
    o.z = w0 * bf2f((unsigned short)(p0.y & 0xffff)) + w1 * bf2f((unsigned short)(p1.y & 0xffff));
    o.w = w0 * bf2f((unsigned short)(p0.y >> 16))    + w1 * bf2f((unsigned short)(p1.y >> 16));
    *(float4*)(out + (size_t)n * DDIM + t * 4) = o;
}

// ---------------- aux loss ----------------
__global__ void aux_kernel(const float* __restrict__ stats, float* __restrict__ out)
{
    if (threadIdx.x == 0 && blockIdx.x == 0) {
        float ps[NEXP], cn[NEXP], z = 0.f;
#pragma unroll
        for (int e = 0; e < NEXP; e++) { ps[e] = 0.f; cn[e] = 0.f; }
        for (int c = 0; c < 64; c++) {
            const float* sp = stats + c * 17;
#pragma unroll
            for (int e = 0; e < NEXP; e++) { ps[e] += sp[e]; cn[e] += sp[8 + e]; }
            z += sp[16];
        }
        float lb = 0.f;
#pragma unroll
        for (int e = 0; e < NEXP; e++)
            lb += (cn[e] / (2.f * N_TOK)) * (ps[e] / N_TOK);
        const float aux = 0.01f * 8.f * lb + 0.001f * (z / N_TOK);
        out[(size_t)N_TOK * DDIM] = aux;
    }
}

extern "C" void kernel_launch(void* const* d_in, const int* in_sizes, int n_in,
                              void* d_out, int out_size, void* d_ws, size_t ws_size,
                              hipStream_t stream)
{
    (void)in_sizes; (void)n_in; (void)ws_size; (void)out_size;
    const float* x       = (const float*)d_in[0];
    const float* gate_w  = (const float*)d_in[1];
    const float* wi_gate = (const float*)d_in[2];
    const float* wi_up   = (const float*)d_in[3];
    const float* wo      = (const float*)d_in[4];
    float* out = (float*)d_out;
    char* ws = (char*)d_ws;

    // workspace layout (~433 MB)
    int*            topk_idx = (int*)(ws + 0);          //  65536 B
    float*          topk_w   = (float*)(ws + 65536);    //  65536 B
    int*            slot_tok = (int*)(ws + 131072);     //  81920 B
    int*            tok2slot = (int*)(ws + 212992);     //  65536 B
    float*          stats    = (float*)(ws + 278528);   //   4352 B
    int*            gcnt     = (int*)(ws + 282880);     //     64 B
    unsigned short* disp     = (unsigned short*)(ws + 524288);     //  41943040 B
    unsigned short* act      = (unsigned short*)(ws + 42467328);   // 167772160 B
    unsigned short* eout     = (unsigned short*)(ws + 210239488);  //  41943040 B
    unsigned short* wcomb    = (unsigned short*)(ws + 252182528);  // 134217728 B
    unsigned short* wo_bf    = (unsigned short*)(ws + 386400256);  //  67108864 B -> end 453509120

    hipMemsetAsync(stats, 0, 64 * 17 * sizeof(float), stream);

    convert_wi_kernel<<<32768, 256, 0, stream>>>(wi_gate, wi_up, wcomb);
    convert_wo_kernel<<<16384, 256, 0, stream>>>(wo, wo_bf);
    router_kernel<<<N_TOK / 4, 256, 0, stream>>>(x, gate_w, topk_idx, topk_w, stats);
    pos_kernel<<<1, 512, 0, stream>>>(topk_idx, topk_w, slot_tok, tok2slot, gcnt);
    dispatch_kernel<<<NSLOT, 128, 0, stream>>>(x, slot_tok, disp);
    gemm1_kernel<<<NEXP * 20 * 64, 256, 0, stream>>>(disp, wcomb, gcnt, act);
    gemm2_kernel<<<NEXP * 20 * 8, 256, 0, stream>>>(act, wo_bf, gcnt, eout);
    combine_kernel<<<N_TOK, 256, 0, stream>>>(eout, tok2slot, topk_w, out);
    aux_kernel<<<1, 64, 0, stream>>>(stats, out);
}